// Round 5
// baseline (229.330 us; speedup 1.0000x reference)
//
#include <hip/hip_runtime.h>
#include <math.h>

#define NN 50000
#define EE 400000
#define HD 256
#define NH 4
#define DH 64
#define NEG_SLOPE 0.2f

typedef __attribute__((ext_vector_type(8))) __bf16 bf16x8;
typedef __attribute__((ext_vector_type(4))) float f32x4;

__device__ __forceinline__ float bf2f(unsigned short h) {
  return __uint_as_float(((unsigned)h) << 16);
}

// ============================ CSR build ============================
__global__ void k_zero_i32(int* __restrict__ p, int n) {
  int i = blockIdx.x * blockDim.x + threadIdx.x;
  if (i < n) p[i] = 0;
}

__global__ void k_count(const int* __restrict__ dst, int* __restrict__ counts,
                        int* __restrict__ rank) {
  int e = blockIdx.x * blockDim.x + threadIdx.x;
  if (e < EE) rank[e] = atomicAdd(&counts[dst[e]], 1);
}

__global__ void k_scan1(const int* __restrict__ counts, int* __restrict__ row_ptr,
                        int* __restrict__ bsums) {
  __shared__ int sm[256];
  int i = blockIdx.x * 256 + threadIdx.x;
  int v = (i < NN) ? counts[i] : 0;
  sm[threadIdx.x] = v;
  __syncthreads();
  for (int off = 1; off < 256; off <<= 1) {
    int t = (threadIdx.x >= off) ? sm[threadIdx.x - off] : 0;
    __syncthreads();
    sm[threadIdx.x] += t;
    __syncthreads();
  }
  if (i < NN) row_ptr[i + 1] = sm[threadIdx.x];
  if (threadIdx.x == 255) bsums[blockIdx.x] = sm[255];
}

__global__ void k_scan2(int* __restrict__ bsums, int nb) {
  __shared__ int sm[256];
  int v = (threadIdx.x < nb) ? bsums[threadIdx.x] : 0;
  sm[threadIdx.x] = v;
  __syncthreads();
  for (int off = 1; off < 256; off <<= 1) {
    int t = (threadIdx.x >= off) ? sm[threadIdx.x - off] : 0;
    __syncthreads();
    sm[threadIdx.x] += t;
    __syncthreads();
  }
  if (threadIdx.x < nb) bsums[threadIdx.x] = sm[threadIdx.x] - v;  // exclusive
}

__global__ void k_scan3(int* __restrict__ row_ptr, const int* __restrict__ bsums) {
  int i = blockIdx.x * 256 + threadIdx.x;
  if (i < NN) row_ptr[i + 1] += bsums[blockIdx.x];
  if (blockIdx.x == 0 && threadIdx.x == 0) row_ptr[0] = 0;
}

__global__ void k_scatter(const int* __restrict__ src, const int* __restrict__ dst,
                          const int* __restrict__ row_ptr, const int* __restrict__ rank,
                          int* __restrict__ csr_src) {
  int e = blockIdx.x * blockDim.x + threadIdx.x;
  if (e < EE) csr_src[row_ptr[dst[e]] + rank[e]] = src[e];
}

// ============================ W prep ============================
// Wt_pre layout (bf16): [k_blk 0..7][khalf 0..3][n 0..255][j 0..7]
// element (k,n) -> (k>>5)*8192 + ((k>>3)&3)*2048 + n*8 + (k&7)
__global__ __launch_bounds__(256) void k_prep_w2(const float* __restrict__ W1,
                                                 const float* __restrict__ W2,
                                                 __bf16* __restrict__ W1H,
                                                 __bf16* __restrict__ W1L,
                                                 __bf16* __restrict__ W2H,
                                                 __bf16* __restrict__ W2L) {
  int b = blockIdx.x;
  const float* W = (b < 256) ? W1 : W2;
  __bf16* WH = (b < 256) ? W1H : W2H;
  __bf16* WL = (b < 256) ? W1L : W2L;
  int t = (b & 255) * 256 + threadIdx.x;  // 65536
  int n = t & 255, k = t >> 8;
  float x = W[(size_t)k * 256 + n];
  __bf16 h = (__bf16)x;
  size_t o = (size_t)(k >> 5) * 8192 + (size_t)((k >> 3) & 3) * 2048 + (size_t)n * 8 + (k & 7);
  WH[o] = h;
  WL[o] = (__bf16)(x - (float)h);
}

// ============================ MFMA GEMM (LDS-free, barrier-free) ============================
// f[M,256](bf16) = A[idx[m],256] @ W ; split-bf16: Ah@Wh + Ah@Wl + Al@Wh
// Each lane loads its MFMA fragments DIRECTLY from global:
//   A-frag: row = row0+mf*16+(lane&15), k = kb*32+(lane>>4)*8+j  (fp32->hi/lo in reg)
//   B-frag: pre-tiled W, contiguous 16B at kb*8192+khalf*2048+n*8
// W (256KB) is L2-resident; A tile re-read by the 4 waves (L2 hits).
// No __syncthreads -> compiler software-pipelines the K loop; waves never lockstep.
__global__ __launch_bounds__(256) void k_gemm_mfma(
    const float* __restrict__ A, const int* __restrict__ idx,
    const __bf16* __restrict__ WtH, const __bf16* __restrict__ WtL,
    const float* __restrict__ al, const float* __restrict__ ar,
    __bf16* __restrict__ C, float* __restrict__ el, float* __restrict__ er,
    int Mrows) {
  int tid = threadIdx.x;
  int lane = tid & 63;
  int w = tid >> 6;           // wave = head
  int row0 = blockIdx.x * 64;
  int khalf = lane >> 4;
  int l15 = lane & 15;

  f32x4 acc[4][4];
#pragma unroll
  for (int i = 0; i < 4; ++i)
#pragma unroll
    for (int j = 0; j < 4; ++j) acc[i][j] = (f32x4){0.f, 0.f, 0.f, 0.f};

  // per-lane A row base pointers (clamped; OOB rows produce garbage that is never stored)
  const float* ap[4];
#pragma unroll
  for (int mf = 0; mf < 4; ++mf) {
    int r = row0 + mf * 16 + l15;
    r = (r < Mrows) ? r : (Mrows - 1);
    int arow = idx ? idx[r] : r;
    ap[mf] = A + (size_t)arow * HD + khalf * 8;
  }
  const __bf16* bhbase = WtH + (size_t)khalf * 2048 + ((size_t)w * 64 + l15) * 8;
  const __bf16* blbase = WtL + (size_t)khalf * 2048 + ((size_t)w * 64 + l15) * 8;

#pragma unroll 2
  for (int kb = 0; kb < 8; ++kb) {
    bf16x8 ah[4], alo[4], bh[4], blo[4];
#pragma unroll
    for (int nf = 0; nf < 4; ++nf) {
      bh[nf] = *(const bf16x8*)(bhbase + (size_t)kb * 8192 + nf * 128);
      blo[nf] = *(const bf16x8*)(blbase + (size_t)kb * 8192 + nf * 128);
    }
#pragma unroll
    for (int mf = 0; mf < 4; ++mf) {
      float xx[8];
      *(float4*)&xx[0] = *(const float4*)(ap[mf] + kb * 32);
      *(float4*)&xx[4] = *(const float4*)(ap[mf] + kb * 32 + 4);
      bf16x8 hv, lv;
#pragma unroll
      for (int i = 0; i < 8; ++i) {
        __bf16 h = (__bf16)xx[i];
        hv[i] = h;
        lv[i] = (__bf16)(xx[i] - (float)h);
      }
      ah[mf] = hv;
      alo[mf] = lv;
    }
#pragma unroll
    for (int mf = 0; mf < 4; ++mf)
#pragma unroll
      for (int nf = 0; nf < 4; ++nf) {
        acc[mf][nf] = __builtin_amdgcn_mfma_f32_16x16x32_bf16(ah[mf], bh[nf], acc[mf][nf], 0, 0, 0);
        acc[mf][nf] = __builtin_amdgcn_mfma_f32_16x16x32_bf16(ah[mf], blo[nf], acc[mf][nf], 0, 0, 0);
        acc[mf][nf] = __builtin_amdgcn_mfma_f32_16x16x32_bf16(alo[mf], bh[nf], acc[mf][nf], 0, 0, 0);
      }
  }

  // ---- epilogue: bf16 C store + fused el/er ----
  float alv[4], arv[4];
#pragma unroll
  for (int nf = 0; nf < 4; ++nf) {
    alv[nf] = al[w * 64 + nf * 16 + l15];
    arv[nf] = ar[w * 64 + nf * 16 + l15];
  }
#pragma unroll
  for (int mf = 0; mf < 4; ++mf) {
#pragma unroll
    for (int r = 0; r < 4; ++r) {
      int row = row0 + mf * 16 + (lane >> 4) * 4 + r;
      bool rv = row < Mrows;
      float se = 0.f, sr = 0.f;
#pragma unroll
      for (int nf = 0; nf < 4; ++nf) {
        float v = acc[mf][nf][r];
        se = fmaf(v, alv[nf], se);
        sr = fmaf(v, arv[nf], sr);
        if (rv) C[(size_t)row * HD + w * 64 + nf * 16 + l15] = (__bf16)v;
      }
#pragma unroll
      for (int off = 1; off < 16; off <<= 1) {
        se += __shfl_xor(se, off);
        sr += __shfl_xor(sr, off);
      }
      if (rv && l15 == 0) {
        el[row * NH + w] = se;
        er[row * NH + w] = sr;
      }
    }
  }
}

// ============================ aggregation ============================
// One wave per dst node; 8-deep batched gather in the accumulate loop.
__global__ __launch_bounds__(256) void k_aggregate(const __bf16* __restrict__ f,
                                                   const float* __restrict__ el,
                                                   const float* __restrict__ er,
                                                   const int* __restrict__ row_ptr,
                                                   const int* __restrict__ csr_src,
                                                   const float* __restrict__ bias,
                                                   float* __restrict__ out, int act) {
  int node = blockIdx.x * 4 + (threadIdx.x >> 6);
  if (node >= NN) return;
  int lane = threadIdx.x & 63;
  int start = row_ptr[node];
  int deg = row_ptr[node + 1] - start;

  float ern = er[node * NH + (lane & 3)];

  int sreg[4];
  float ereg[4];
  float mloc = -INFINITY;
#pragma unroll
  for (int c = 0; c < 4; ++c) {
    int j = c * 16 + (lane >> 2);
    int s = 0;
    float e = -INFINITY;
    if (c * 16 < deg && j < deg) {
      s = csr_src[start + j];
      e = el[s * NH + (lane & 3)] + ern;
      e = (e >= 0.f) ? e : NEG_SLOPE * e;
    }
    sreg[c] = s;
    ereg[c] = e;
    mloc = fmaxf(mloc, e);
  }
  for (int j0 = 64; j0 < deg; j0 += 16) {  // rare tail
    int j = j0 + (lane >> 2);
    if (j < deg) {
      int s = csr_src[start + j];
      float e = el[s * NH + (lane & 3)] + ern;
      e = (e >= 0.f) ? e : NEG_SLOPE * e;
      mloc = fmaxf(mloc, e);
    }
  }
  float mm = mloc;
#pragma unroll
  for (int off = 4; off < 64; off <<= 1) mm = fmaxf(mm, __shfl_xor(mm, off));

  float vreg[4];
  float vloc = 0.f;
#pragma unroll
  for (int c = 0; c < 4; ++c) {
    float v = (ereg[c] > -INFINITY) ? __expf(ereg[c] - mm) : 0.f;
    vreg[c] = v;
    vloc += v;
  }
  for (int j0 = 64; j0 < deg; j0 += 16) {  // rare tail
    int j = j0 + (lane >> 2);
    if (j < deg) {
      int s = csr_src[start + j];
      float e = el[s * NH + (lane & 3)] + ern;
      e = (e >= 0.f) ? e : NEG_SLOPE * e;
      vloc += __expf(e - mm);
    }
  }
  float ss = vloc;
#pragma unroll
  for (int off = 4; off < 64; off <<= 1) ss += __shfl_xor(ss, off);

  float inv_own = (ss > 0.f) ? (1.f / ss) : 0.f;
  float areg[4];
#pragma unroll
  for (int c = 0; c < 4; ++c) areg[c] = vreg[c] * inv_own;

  int head = lane >> 4;

  float4 acc = ((const float4*)bias)[lane];
  for (int c = 0; c < 4; ++c) {
    int base = c * 16;
    if (base >= deg) break;
    int cnt = deg - base;
    cnt = (cnt > 16) ? 16 : cnt;
    for (int g = 0; g < cnt; g += 8) {
      ushort4 u[8];
      float aa[8];
#pragma unroll
      for (int jj = 0; jj < 8; ++jj) {
        int j = g + jj;
        int jc = (j < cnt) ? j : (cnt - 1);   // clamp: duplicate row, a=0
        int srcl = jc * 4 + head;
        int s = __shfl(sreg[c], srcl);
        float a = __shfl(areg[c], srcl);
        aa[jj] = (j < cnt) ? a : 0.f;
        u[jj] = ((const ushort4*)(f + (size_t)s * HD))[lane];
      }
#pragma unroll
      for (int jj = 0; jj < 8; ++jj) {
        acc.x = fmaf(aa[jj], bf2f(u[jj].x), acc.x);
        acc.y = fmaf(aa[jj], bf2f(u[jj].y), acc.y);
        acc.z = fmaf(aa[jj], bf2f(u[jj].z), acc.z);
        acc.w = fmaf(aa[jj], bf2f(u[jj].w), acc.w);
      }
    }
  }
  if (deg > 64) {  // rare tail
    float mH = __shfl(mm, head);
    float sH = __shfl(ss, head);
    float erH = __shfl(ern, head);
    float invH = (sH > 0.f) ? (1.f / sH) : 0.f;
    for (int j = 64; j < deg; ++j) {
      int s = csr_src[start + j];
      float e = el[s * NH + head] + erH;
      e = (e >= 0.f) ? e : NEG_SLOPE * e;
      float a = __expf(e - mH) * invH;
      ushort4 u = ((const ushort4*)(f + (size_t)s * HD))[lane];
      acc.x = fmaf(a, bf2f(u.x), acc.x);
      acc.y = fmaf(a, bf2f(u.y), acc.y);
      acc.z = fmaf(a, bf2f(u.z), acc.z);
      acc.w = fmaf(a, bf2f(u.w), acc.w);
    }
  }

  if (act) {
    acc.x = (acc.x > 0.f) ? acc.x : __expf(acc.x) - 1.f;
    acc.y = (acc.y > 0.f) ? acc.y : __expf(acc.y) - 1.f;
    acc.z = (acc.z > 0.f) ? acc.z : __expf(acc.z) - 1.f;
    acc.w = (acc.w > 0.f) ? acc.w : __expf(acc.w) - 1.f;
  }
  ((float4*)(out + (size_t)node * HD))[lane] = acc;
}

// ============================ launch ============================
extern "C" void kernel_launch(void* const* d_in, const int* in_sizes, int n_in,
                              void* d_out, int out_size, void* d_ws, size_t ws_size,
                              hipStream_t stream) {
  const int* nids = (const int*)d_in[0];
  const int* esrc = (const int*)d_in[1];
  const int* edst = (const int*)d_in[2];
  const float* emb = (const float*)d_in[3];
  const float* W1 = (const float*)d_in[4];
  const float* al1 = (const float*)d_in[5];
  const float* ar1 = (const float*)d_in[6];
  const float* b1 = (const float*)d_in[7];
  const float* W2 = (const float*)d_in[8];
  const float* al2 = (const float*)d_in[9];
  const float* ar2 = (const float*)d_in[10];
  const float* b2 = (const float*)d_in[11];
  float* out = (float*)d_out;

  char* w = (char*)d_ws;
  size_t off = 0;
  auto alloc = [&](size_t bytes) {
    void* p = w + off;
    off += (bytes + 255) & ~(size_t)255;  // 256B-align every buffer
    return p;
  };
  __bf16* fbuf = (__bf16*)alloc((size_t)NN * HD * 2);
  float* el = (float*)alloc((size_t)NN * NH * 4);
  float* er = (float*)alloc((size_t)NN * NH * 4);
  int* row_ptr = (int*)alloc((size_t)(NN + 1) * 4);
  int* counts = (int*)alloc((size_t)NN * 4);
  int* rank = (int*)alloc((size_t)EE * 4);
  int* csr_src = (int*)alloc((size_t)EE * 4);
  int* bsums = (int*)alloc(1024);
  __bf16* W1tH = (__bf16*)alloc((size_t)HD * HD * 2);
  __bf16* W1tL = (__bf16*)alloc((size_t)HD * HD * 2);
  __bf16* W2tH = (__bf16*)alloc((size_t)HD * HD * 2);
  __bf16* W2tL = (__bf16*)alloc((size_t)HD * HD * 2);

  int nbN = (NN + 255) / 256;
  int nbE = (EE + 255) / 256;

  k_zero_i32<<<nbN, 256, 0, stream>>>(counts, NN);
  k_count<<<nbE, 256, 0, stream>>>(edst, counts, rank);
  k_scan1<<<nbN, 256, 0, stream>>>(counts, row_ptr, bsums);
  k_scan2<<<1, 256, 0, stream>>>(bsums, nbN);
  k_scan3<<<nbN, 256, 0, stream>>>(row_ptr, bsums);
  k_scatter<<<nbE, 256, 0, stream>>>(esrc, edst, row_ptr, rank, csr_src);
  k_prep_w2<<<512, 256, 0, stream>>>(W1, W2, W1tH, W1tL, W2tH, W2tL);

  int gemm_grid = (NN + 63) / 64;
  int nbNode4 = (NN + 3) / 4;

  // ---- layer 1 ----
  k_gemm_mfma<<<gemm_grid, 256, 0, stream>>>(emb, nids, W1tH, W1tL, al1, ar1,
                                             fbuf, el, er, NN);
  k_aggregate<<<nbNode4, 256, 0, stream>>>(fbuf, el, er, row_ptr, csr_src, b1, out, 1);

  // ---- layer 2 ----
  k_gemm_mfma<<<gemm_grid, 256, 0, stream>>>(out, nullptr, W2tH, W2tL, al2, ar2,
                                             fbuf, el, er, NN);
  k_aggregate<<<nbNode4, 256, 0, stream>>>(fbuf, el, er, row_ptr, csr_src, b2, out, 0);
}

// Round 6
// 215.779 us; speedup vs baseline: 1.0628x; 1.0628x over previous
//
#include <hip/hip_runtime.h>
#include <math.h>

#define NN 50000
#define EE 400000
#define HD 256
#define NH 4
#define DH 64
#define NEG_SLOPE 0.2f

typedef __attribute__((ext_vector_type(8))) __bf16 bf16x8;
typedef __attribute__((ext_vector_type(4))) float f32x4;

__device__ __forceinline__ float bf2f(unsigned short h) {
  return __uint_as_float(((unsigned)h) << 16);
}

// ============================ CSR build ============================
__global__ void k_zero_i32(int* __restrict__ p, int n) {
  int i = blockIdx.x * blockDim.x + threadIdx.x;
  if (i < n) p[i] = 0;
}

__global__ void k_count(const int* __restrict__ dst, int* __restrict__ counts,
                        int* __restrict__ rank) {
  int e = blockIdx.x * blockDim.x + threadIdx.x;
  if (e < EE) rank[e] = atomicAdd(&counts[dst[e]], 1);
}

__global__ void k_scan1(const int* __restrict__ counts, int* __restrict__ row_ptr,
                        int* __restrict__ bsums) {
  __shared__ int sm[256];
  int i = blockIdx.x * 256 + threadIdx.x;
  int v = (i < NN) ? counts[i] : 0;
  sm[threadIdx.x] = v;
  __syncthreads();
  for (int off = 1; off < 256; off <<= 1) {
    int t = (threadIdx.x >= off) ? sm[threadIdx.x - off] : 0;
    __syncthreads();
    sm[threadIdx.x] += t;
    __syncthreads();
  }
  if (i < NN) row_ptr[i + 1] = sm[threadIdx.x];
  if (threadIdx.x == 255) bsums[blockIdx.x] = sm[255];
}

__global__ void k_scan2(int* __restrict__ bsums, int nb) {
  __shared__ int sm[256];
  int v = (threadIdx.x < nb) ? bsums[threadIdx.x] : 0;
  sm[threadIdx.x] = v;
  __syncthreads();
  for (int off = 1; off < 256; off <<= 1) {
    int t = (threadIdx.x >= off) ? sm[threadIdx.x - off] : 0;
    __syncthreads();
    sm[threadIdx.x] += t;
    __syncthreads();
  }
  if (threadIdx.x < nb) bsums[threadIdx.x] = sm[threadIdx.x] - v;  // exclusive
}

__global__ void k_scan3(int* __restrict__ row_ptr, const int* __restrict__ bsums) {
  int i = blockIdx.x * 256 + threadIdx.x;
  if (i < NN) row_ptr[i + 1] += bsums[blockIdx.x];
  if (blockIdx.x == 0 && threadIdx.x == 0) row_ptr[0] = 0;
}

__global__ void k_scatter(const int* __restrict__ src, const int* __restrict__ dst,
                          const int* __restrict__ row_ptr, const int* __restrict__ rank,
                          int* __restrict__ csr_src) {
  int e = blockIdx.x * blockDim.x + threadIdx.x;
  if (e < EE) csr_src[row_ptr[dst[e]] + rank[e]] = src[e];
}

// ============================ W prep ============================
// Wt_pre layout (bf16): [k_blk 0..7][khalf 0..3][n 0..255][j 0..7]
// element (k,n) -> (k>>5)*8192 + ((k>>3)&3)*2048 + n*8 + (k&7)
__global__ __launch_bounds__(256) void k_prep_w2(const float* __restrict__ W1,
                                                 const float* __restrict__ W2,
                                                 __bf16* __restrict__ W1H,
                                                 __bf16* __restrict__ W1L,
                                                 __bf16* __restrict__ W2H,
                                                 __bf16* __restrict__ W2L) {
  int b = blockIdx.x;
  const float* W = (b < 256) ? W1 : W2;
  __bf16* WH = (b < 256) ? W1H : W2H;
  __bf16* WL = (b < 256) ? W1L : W2L;
  int t = (b & 255) * 256 + threadIdx.x;  // 65536
  int n = t & 255, k = t >> 8;
  float x = W[(size_t)k * 256 + n];
  __bf16 h = (__bf16)x;
  size_t o = (size_t)(k >> 5) * 8192 + (size_t)((k >> 3) & 3) * 2048 + (size_t)n * 8 + (k & 7);
  WH[o] = h;
  WL[o] = (__bf16)(x - (float)h);
}

// ============================ MFMA GEMM ============================
// f[M,256](bf16) = A[idx[m],256] @ W ; split-bf16: Ah@Wh + Ah@Wl + Al@Wh
// Block = 128 rows x 64 cols (one head). W-hi slice (32KB) staged to LDS ONCE;
// K-loop is barrier-free: A per-lane from global (L3-stream), B-hi ds_read_b128,
// B-lo per-lane from L2-resident global. 4 waves x 32 rows. Fused el/er epilogue.
__device__ __forceinline__ void gload_lds16(const void* g, void* l) {
  __builtin_amdgcn_global_load_lds((const __attribute__((address_space(1))) void*)g,
                                   (__attribute__((address_space(3))) void*)l, 16, 0, 0);
}

__global__ __launch_bounds__(256, 3) void k_gemm_mfma(
    const float* __restrict__ A, const int* __restrict__ idx,
    const __bf16* __restrict__ WtH, const __bf16* __restrict__ WtL,
    const float* __restrict__ al, const float* __restrict__ ar,
    __bf16* __restrict__ C, float* __restrict__ el, float* __restrict__ er,
    int Mrows) {
  // [kb 0..7][khalf 0..3][col 0..63] of bf16x8 slots = 32KB
  __shared__ bf16x8 BsH[8 * 4 * 64];

  int tid = threadIdx.x;
  int lane = tid & 63;
  int w = tid >> 6;
  int row0 = blockIdx.x * 128;
  int n0 = blockIdx.y * 64;      // head block
  int head = blockIdx.y;
  int khalf = lane >> 4;
  int l15 = lane & 15;

  // ---- stage W-hi slice once: slot = i*256 + w*64 + lane -> (kb=i, kh=w, col=lane)
#pragma unroll
  for (int i = 0; i < 8; ++i) {
    const __bf16* src = WtH + (size_t)i * 8192 + (size_t)w * 2048 + ((size_t)n0 + lane) * 8;
    gload_lds16(src, (void*)&BsH[i * 256 + w * 64]);
  }

  f32x4 acc[2][4];
#pragma unroll
  for (int i = 0; i < 2; ++i)
#pragma unroll
    for (int j = 0; j < 4; ++j) acc[i][j] = (f32x4){0.f, 0.f, 0.f, 0.f};

  // per-lane A row pointers (clamped; OOB rows never stored)
  const float* ap[2];
#pragma unroll
  for (int mf = 0; mf < 2; ++mf) {
    int r = row0 + w * 32 + mf * 16 + l15;
    r = (r < Mrows) ? r : (Mrows - 1);
    int arow = idx ? idx[r] : r;
    ap[mf] = A + (size_t)arow * HD + khalf * 8;
  }
  const __bf16* blbase = WtL + (size_t)khalf * 2048 + ((size_t)n0 + l15) * 8;

  __syncthreads();  // staging complete (the only barrier)

#pragma unroll 2
  for (int kb = 0; kb < 8; ++kb) {
    bf16x8 bh[4], blo[4];
#pragma unroll
    for (int nf = 0; nf < 4; ++nf) {
      bh[nf] = BsH[kb * 256 + khalf * 64 + nf * 16 + l15];
      blo[nf] = *(const bf16x8*)(blbase + (size_t)kb * 8192 + nf * 128);
    }
    bf16x8 ah[2], alo[2];
#pragma unroll
    for (int mf = 0; mf < 2; ++mf) {
      float xx[8];
      *(float4*)&xx[0] = *(const float4*)(ap[mf] + kb * 32);
      *(float4*)&xx[4] = *(const float4*)(ap[mf] + kb * 32 + 4);
      bf16x8 hv, lv;
#pragma unroll
      for (int i = 0; i < 8; ++i) {
        __bf16 h = (__bf16)xx[i];
        hv[i] = h;
        lv[i] = (__bf16)(xx[i] - (float)h);
      }
      ah[mf] = hv;
      alo[mf] = lv;
    }
#pragma unroll
    for (int mf = 0; mf < 2; ++mf)
#pragma unroll
      for (int nf = 0; nf < 4; ++nf) {
        acc[mf][nf] = __builtin_amdgcn_mfma_f32_16x16x32_bf16(ah[mf], bh[nf], acc[mf][nf], 0, 0, 0);
        acc[mf][nf] = __builtin_amdgcn_mfma_f32_16x16x32_bf16(ah[mf], blo[nf], acc[mf][nf], 0, 0, 0);
        acc[mf][nf] = __builtin_amdgcn_mfma_f32_16x16x32_bf16(alo[mf], bh[nf], acc[mf][nf], 0, 0, 0);
      }
  }

  // ---- epilogue: bf16 C store + fused el/er (this block's head) ----
  float alv[4], arv[4];
#pragma unroll
  for (int nf = 0; nf < 4; ++nf) {
    alv[nf] = al[n0 + nf * 16 + l15];
    arv[nf] = ar[n0 + nf * 16 + l15];
  }
#pragma unroll
  for (int mf = 0; mf < 2; ++mf) {
#pragma unroll
    for (int r = 0; r < 4; ++r) {
      int row = row0 + w * 32 + mf * 16 + (lane >> 4) * 4 + r;
      bool rv = row < Mrows;
      float se = 0.f, sr = 0.f;
#pragma unroll
      for (int nf = 0; nf < 4; ++nf) {
        float v = acc[mf][nf][r];
        se = fmaf(v, alv[nf], se);
        sr = fmaf(v, arv[nf], sr);
        if (rv) C[(size_t)row * HD + n0 + nf * 16 + l15] = (__bf16)v;
      }
#pragma unroll
      for (int off = 1; off < 16; off <<= 1) {
        se += __shfl_xor(se, off);
        sr += __shfl_xor(sr, off);
      }
      if (rv && l15 == 0) {
        el[row * NH + head] = se;
        er[row * NH + head] = sr;
      }
    }
  }
}

// ============================ aggregation ============================
// One wave per dst node; 8-deep batched gather in the accumulate loop.
__global__ __launch_bounds__(256) void k_aggregate(const __bf16* __restrict__ f,
                                                   const float* __restrict__ el,
                                                   const float* __restrict__ er,
                                                   const int* __restrict__ row_ptr,
                                                   const int* __restrict__ csr_src,
                                                   const float* __restrict__ bias,
                                                   float* __restrict__ out, int act) {
  int node = blockIdx.x * 4 + (threadIdx.x >> 6);
  if (node >= NN) return;
  int lane = threadIdx.x & 63;
  int start = row_ptr[node];
  int deg = row_ptr[node + 1] - start;

  float ern = er[node * NH + (lane & 3)];

  int sreg[4];
  float ereg[4];
  float mloc = -INFINITY;
#pragma unroll
  for (int c = 0; c < 4; ++c) {
    int j = c * 16 + (lane >> 2);
    int s = 0;
    float e = -INFINITY;
    if (c * 16 < deg && j < deg) {
      s = csr_src[start + j];
      e = el[s * NH + (lane & 3)] + ern;
      e = (e >= 0.f) ? e : NEG_SLOPE * e;
    }
    sreg[c] = s;
    ereg[c] = e;
    mloc = fmaxf(mloc, e);
  }
  for (int j0 = 64; j0 < deg; j0 += 16) {  // rare tail
    int j = j0 + (lane >> 2);
    if (j < deg) {
      int s = csr_src[start + j];
      float e = el[s * NH + (lane & 3)] + ern;
      e = (e >= 0.f) ? e : NEG_SLOPE * e;
      mloc = fmaxf(mloc, e);
    }
  }
  float mm = mloc;
#pragma unroll
  for (int off = 4; off < 64; off <<= 1) mm = fmaxf(mm, __shfl_xor(mm, off));

  float vreg[4];
  float vloc = 0.f;
#pragma unroll
  for (int c = 0; c < 4; ++c) {
    float v = (ereg[c] > -INFINITY) ? __expf(ereg[c] - mm) : 0.f;
    vreg[c] = v;
    vloc += v;
  }
  for (int j0 = 64; j0 < deg; j0 += 16) {  // rare tail
    int j = j0 + (lane >> 2);
    if (j < deg) {
      int s = csr_src[start + j];
      float e = el[s * NH + (lane & 3)] + ern;
      e = (e >= 0.f) ? e : NEG_SLOPE * e;
      vloc += __expf(e - mm);
    }
  }
  float ss = vloc;
#pragma unroll
  for (int off = 4; off < 64; off <<= 1) ss += __shfl_xor(ss, off);

  float inv_own = (ss > 0.f) ? (1.f / ss) : 0.f;
  float areg[4];
#pragma unroll
  for (int c = 0; c < 4; ++c) areg[c] = vreg[c] * inv_own;

  int head = lane >> 4;

  float4 acc = ((const float4*)bias)[lane];
  for (int c = 0; c < 4; ++c) {
    int base = c * 16;
    if (base >= deg) break;
    int cnt = deg - base;
    cnt = (cnt > 16) ? 16 : cnt;
    for (int g = 0; g < cnt; g += 8) {
      ushort4 u[8];
      float aa[8];
#pragma unroll
      for (int jj = 0; jj < 8; ++jj) {
        int j = g + jj;
        int jc = (j < cnt) ? j : (cnt - 1);   // clamp: duplicate row, a=0
        int srcl = jc * 4 + head;
        int s = __shfl(sreg[c], srcl);
        float a = __shfl(areg[c], srcl);
        aa[jj] = (j < cnt) ? a : 0.f;
        u[jj] = ((const ushort4*)(f + (size_t)s * HD))[lane];
      }
#pragma unroll
      for (int jj = 0; jj < 8; ++jj) {
        acc.x = fmaf(aa[jj], bf2f(u[jj].x), acc.x);
        acc.y = fmaf(aa[jj], bf2f(u[jj].y), acc.y);
        acc.z = fmaf(aa[jj], bf2f(u[jj].z), acc.z);
        acc.w = fmaf(aa[jj], bf2f(u[jj].w), acc.w);
      }
    }
  }
  if (deg > 64) {  // rare tail
    float mH = __shfl(mm, head);
    float sH = __shfl(ss, head);
    float erH = __shfl(ern, head);
    float invH = (sH > 0.f) ? (1.f / sH) : 0.f;
    for (int j = 64; j < deg; ++j) {
      int s = csr_src[start + j];
      float e = el[s * NH + head] + erH;
      e = (e >= 0.f) ? e : NEG_SLOPE * e;
      float a = __expf(e - mH) * invH;
      ushort4 u = ((const ushort4*)(f + (size_t)s * HD))[lane];
      acc.x = fmaf(a, bf2f(u.x), acc.x);
      acc.y = fmaf(a, bf2f(u.y), acc.y);
      acc.z = fmaf(a, bf2f(u.z), acc.z);
      acc.w = fmaf(a, bf2f(u.w), acc.w);
    }
  }

  if (act) {
    acc.x = (acc.x > 0.f) ? acc.x : __expf(acc.x) - 1.f;
    acc.y = (acc.y > 0.f) ? acc.y : __expf(acc.y) - 1.f;
    acc.z = (acc.z > 0.f) ? acc.z : __expf(acc.z) - 1.f;
    acc.w = (acc.w > 0.f) ? acc.w : __expf(acc.w) - 1.f;
  }
  ((float4*)(out + (size_t)node * HD))[lane] = acc;
}

// ============================ launch ============================
extern "C" void kernel_launch(void* const* d_in, const int* in_sizes, int n_in,
                              void* d_out, int out_size, void* d_ws, size_t ws_size,
                              hipStream_t stream) {
  const int* nids = (const int*)d_in[0];
  const int* esrc = (const int*)d_in[1];
  const int* edst = (const int*)d_in[2];
  const float* emb = (const float*)d_in[3];
  const float* W1 = (const float*)d_in[4];
  const float* al1 = (const float*)d_in[5];
  const float* ar1 = (const float*)d_in[6];
  const float* b1 = (const float*)d_in[7];
  const float* W2 = (const float*)d_in[8];
  const float* al2 = (const float*)d_in[9];
  const float* ar2 = (const float*)d_in[10];
  const float* b2 = (const float*)d_in[11];
  float* out = (float*)d_out;

  char* w = (char*)d_ws;
  size_t off = 0;
  auto alloc = [&](size_t bytes) {
    void* p = w + off;
    off += (bytes + 255) & ~(size_t)255;  // 256B-align every buffer
    return p;
  };
  __bf16* fbuf = (__bf16*)alloc((size_t)NN * HD * 2);
  float* el = (float*)alloc((size_t)NN * NH * 4);
  float* er = (float*)alloc((size_t)NN * NH * 4);
  int* row_ptr = (int*)alloc((size_t)(NN + 1) * 4);
  int* counts = (int*)alloc((size_t)NN * 4);
  int* rank = (int*)alloc((size_t)EE * 4);
  int* csr_src = (int*)alloc((size_t)EE * 4);
  int* bsums = (int*)alloc(1024);
  __bf16* W1tH = (__bf16*)alloc((size_t)HD * HD * 2);
  __bf16* W1tL = (__bf16*)alloc((size_t)HD * HD * 2);
  __bf16* W2tH = (__bf16*)alloc((size_t)HD * HD * 2);
  __bf16* W2tL = (__bf16*)alloc((size_t)HD * HD * 2);

  int nbN = (NN + 255) / 256;
  int nbE = (EE + 255) / 256;

  k_zero_i32<<<nbN, 256, 0, stream>>>(counts, NN);
  k_count<<<nbE, 256, 0, stream>>>(edst, counts, rank);
  k_scan1<<<nbN, 256, 0, stream>>>(counts, row_ptr, bsums);
  k_scan2<<<1, 256, 0, stream>>>(bsums, nbN);
  k_scan3<<<nbN, 256, 0, stream>>>(row_ptr, bsums);
  k_scatter<<<nbE, 256, 0, stream>>>(esrc, edst, row_ptr, rank, csr_src);
  k_prep_w2<<<512, 256, 0, stream>>>(W1, W2, W1tH, W1tL, W2tH, W2tL);

  dim3 gemm_grid((NN + 127) / 128, NH);  // 391 x 4
  int nbNode4 = (NN + 3) / 4;

  // ---- layer 1 ----
  k_gemm_mfma<<<gemm_grid, 256, 0, stream>>>(emb, nids, W1tH, W1tL, al1, ar1,
                                             fbuf, el, er, NN);
  k_aggregate<<<nbNode4, 256, 0, stream>>>(fbuf, el, er, row_ptr, csr_src, b1, out, 1);

  // ---- layer 2 ----
  k_gemm_mfma<<<gemm_grid, 256, 0, stream>>>(out, nullptr, W2tH, W2tL, al2, ar2,
                                             fbuf, el, er, NN);
  k_aggregate<<<nbNode4, 256, 0, stream>>>(fbuf, el, er, row_ptr, csr_src, b2, out, 0);
}

// Round 7
// 182.539 us; speedup vs baseline: 1.2563x; 1.1821x over previous
//
#include <hip/hip_runtime.h>
#include <math.h>

#define NN 50000
#define EE 400000
#define HD 256
#define NH 4
#define DH 64
#define NEG_SLOPE 0.2f
#define NTILES 3125   // 50000/16 exact

typedef __attribute__((ext_vector_type(8))) _Float16 f16x8;
typedef __attribute__((ext_vector_type(4))) float f32x4;

__device__ __forceinline__ float bf2f(unsigned short h) {
  return __uint_as_float(((unsigned)h) << 16);
}

// ============================ CSR build ============================
__global__ void k_zero_i32(int* __restrict__ p, int n) {
  int i = blockIdx.x * blockDim.x + threadIdx.x;
  if (i < n) p[i] = 0;
}

__global__ void k_count(const int* __restrict__ dst, int* __restrict__ counts,
                        int* __restrict__ rank) {
  int e = blockIdx.x * blockDim.x + threadIdx.x;
  if (e < EE) rank[e] = atomicAdd(&counts[dst[e]], 1);
}

__global__ void k_scan1(const int* __restrict__ counts, int* __restrict__ row_ptr,
                        int* __restrict__ bsums) {
  __shared__ int sm[256];
  int i = blockIdx.x * 256 + threadIdx.x;
  int v = (i < NN) ? counts[i] : 0;
  sm[threadIdx.x] = v;
  __syncthreads();
  for (int off = 1; off < 256; off <<= 1) {
    int t = (threadIdx.x >= off) ? sm[threadIdx.x - off] : 0;
    __syncthreads();
    sm[threadIdx.x] += t;
    __syncthreads();
  }
  if (i < NN) row_ptr[i + 1] = sm[threadIdx.x];
  if (threadIdx.x == 255) bsums[blockIdx.x] = sm[255];
}

__global__ void k_scan2(int* __restrict__ bsums, int nb) {
  __shared__ int sm[256];
  int v = (threadIdx.x < nb) ? bsums[threadIdx.x] : 0;
  sm[threadIdx.x] = v;
  __syncthreads();
  for (int off = 1; off < 256; off <<= 1) {
    int t = (threadIdx.x >= off) ? sm[threadIdx.x - off] : 0;
    __syncthreads();
    sm[threadIdx.x] += t;
    __syncthreads();
  }
  if (threadIdx.x < nb) bsums[threadIdx.x] = sm[threadIdx.x] - v;  // exclusive
}

__global__ void k_scan3(int* __restrict__ row_ptr, const int* __restrict__ bsums) {
  int i = blockIdx.x * 256 + threadIdx.x;
  if (i < NN) row_ptr[i + 1] += bsums[blockIdx.x];
  if (blockIdx.x == 0 && threadIdx.x == 0) row_ptr[0] = 0;
}

__global__ void k_scatter(const int* __restrict__ src, const int* __restrict__ dst,
                          const int* __restrict__ row_ptr, const int* __restrict__ rank,
                          int* __restrict__ csr_src) {
  int e = blockIdx.x * blockDim.x + threadIdx.x;
  if (e < EE) csr_src[row_ptr[dst[e]] + rank[e]] = src[e];
}

// ============================ W prep (fp16, pre-tiled) ============================
// layout: [kb 0..7][khalf 0..3][n 0..255][j 0..7], element (k,n):
//   o = (k>>5)*8192 + ((k>>3)&3)*2048 + n*8 + (k&7)
__global__ __launch_bounds__(256) void k_prep_w2(const float* __restrict__ W1,
                                                 const float* __restrict__ W2,
                                                 _Float16* __restrict__ W1t,
                                                 _Float16* __restrict__ W2t) {
  int b = blockIdx.x;
  const float* W = (b < 256) ? W1 : W2;
  _Float16* Wt = (b < 256) ? W1t : W2t;
  int t = (b & 255) * 256 + threadIdx.x;  // 65536
  int n = t & 255, k = t >> 8;
  float x = W[(size_t)k * 256 + n];
  size_t o = (size_t)(k >> 5) * 8192 + (size_t)((k >> 3) & 3) * 2048 + (size_t)n * 8 + (k & 7);
  Wt[o] = (_Float16)x;
}

// ============================ MFMA GEMM ============================
// f[M,256](bf16) = A[idx[m],256] @ W ; fp16-split A: (Ah+Al)@W(fp16).
// Whole W (128KB fp16, pre-tiled) resident in LDS, staged once, ONE barrier.
// 12 waves x one 16-row x full-N tile each; K-loop barrier-free.
// Fused epilogue: el/er (float4 per row) + bf16 C.
__device__ __forceinline__ void gload_lds16(const void* g, void* l) {
  __builtin_amdgcn_global_load_lds((const __attribute__((address_space(1))) void*)g,
                                   (__attribute__((address_space(3))) void*)l, 16, 0, 0);
}

__global__ __launch_bounds__(768, 3) void k_gemm_mfma(
    const float* __restrict__ A, const int* __restrict__ idx,
    const _Float16* __restrict__ Wt,
    const float* __restrict__ al, const float* __restrict__ ar,
    __bf16* __restrict__ C, float* __restrict__ el, float* __restrict__ er) {
  __shared__ f16x8 Bs[8192];  // 128KB: chunk = (kb*4+khalf)*256 + n

  int tid = threadIdx.x;
  int lane = tid & 63;
  int w = tid >> 6;           // 0..11
  int khalf = lane >> 4;
  int l15 = lane & 15;

  // ---- stage full W once (linear copy, wave-uniform-base + lane*16) ----
  for (int i = tid; i < 8192; i += 768)
    gload_lds16(Wt + (size_t)i * 8, (void*)&Bs[i]);

  float alv[16], arv[16];
#pragma unroll
  for (int nf = 0; nf < 16; ++nf) {
    alv[nf] = al[nf * 16 + l15];
    arv[nf] = ar[nf * 16 + l15];
  }

  int nt = 1;
  int tiles[2];
  tiles[0] = blockIdx.x * 12 + w;                 // 0..3071
  int t2 = 3072 + blockIdx.x;
  if (w == 0 && t2 < NTILES) { tiles[1] = t2; nt = 2; }

  __syncthreads();  // W staged (the only barrier)

  for (int it = 0; it < nt; ++it) {
    int t = tiles[it];
    int row = t * 16 + l15;
    int arow = idx ? idx[row] : row;
    const float* ap = A + (size_t)arow * HD + khalf * 8;

    f32x4 acc[16];
#pragma unroll
    for (int nf = 0; nf < 16; ++nf) acc[nf] = (f32x4){0.f, 0.f, 0.f, 0.f};

#pragma unroll 2
    for (int kb = 0; kb < 8; ++kb) {
      float xx[8];
      *(float4*)&xx[0] = *(const float4*)(ap + kb * 32);
      *(float4*)&xx[4] = *(const float4*)(ap + kb * 32 + 4);
      f16x8 ah, alo;
#pragma unroll
      for (int i = 0; i < 8; ++i) {
        _Float16 h = (_Float16)xx[i];
        ah[i] = h;
        alo[i] = (_Float16)(xx[i] - (float)h);
      }
#pragma unroll
      for (int nf = 0; nf < 16; ++nf) {
        f16x8 bv = Bs[kb * 1024 + khalf * 256 + nf * 16 + l15];
        acc[nf] = __builtin_amdgcn_mfma_f32_16x16x32_f16(ah, bv, acc[nf], 0, 0, 0);
        acc[nf] = __builtin_amdgcn_mfma_f32_16x16x32_f16(alo, bv, acc[nf], 0, 0, 0);
      }
    }

    // ---- epilogue: bf16 C + el/er (rows exact, no bounds checks) ----
    int rowbase = t * 16 + khalf * 4;
#pragma unroll
    for (int r = 0; r < 4; ++r) {
      int row_ = rowbase + r;
      float seh[4], srh[4];
#pragma unroll
      for (int h = 0; h < 4; ++h) {
        float s1 = 0.f, s2 = 0.f;
#pragma unroll
        for (int j = 0; j < 4; ++j) {
          int nf = h * 4 + j;
          float v = acc[nf][r];
          s1 = fmaf(v, alv[nf], s1);
          s2 = fmaf(v, arv[nf], s2);
          C[(size_t)row_ * HD + nf * 16 + l15] = (__bf16)v;
        }
#pragma unroll
        for (int off = 1; off < 16; off <<= 1) {
          s1 += __shfl_xor(s1, off);
          s2 += __shfl_xor(s2, off);
        }
        seh[h] = s1;
        srh[h] = s2;
      }
      if (l15 == 0) {
        *(float4*)&el[row_ * NH] = make_float4(seh[0], seh[1], seh[2], seh[3]);
        *(float4*)&er[row_ * NH] = make_float4(srh[0], srh[1], srh[2], srh[3]);
      }
    }
  }
}

// ============================ aggregation ============================
// One wave per dst node; 8-deep batched gather in the accumulate loop.
__global__ __launch_bounds__(256) void k_aggregate(const __bf16* __restrict__ f,
                                                   const float* __restrict__ el,
                                                   const float* __restrict__ er,
                                                   const int* __restrict__ row_ptr,
                                                   const int* __restrict__ csr_src,
                                                   const float* __restrict__ bias,
                                                   float* __restrict__ out, int act) {
  int node = blockIdx.x * 4 + (threadIdx.x >> 6);
  if (node >= NN) return;
  int lane = threadIdx.x & 63;
  int start = row_ptr[node];
  int deg = row_ptr[node + 1] - start;

  float ern = er[node * NH + (lane & 3)];

  int sreg[4];
  float ereg[4];
  float mloc = -INFINITY;
#pragma unroll
  for (int c = 0; c < 4; ++c) {
    int j = c * 16 + (lane >> 2);
    int s = 0;
    float e = -INFINITY;
    if (c * 16 < deg && j < deg) {
      s = csr_src[start + j];
      e = el[s * NH + (lane & 3)] + ern;
      e = (e >= 0.f) ? e : NEG_SLOPE * e;
    }
    sreg[c] = s;
    ereg[c] = e;
    mloc = fmaxf(mloc, e);
  }
  for (int j0 = 64; j0 < deg; j0 += 16) {  // rare tail
    int j = j0 + (lane >> 2);
    if (j < deg) {
      int s = csr_src[start + j];
      float e = el[s * NH + (lane & 3)] + ern;
      e = (e >= 0.f) ? e : NEG_SLOPE * e;
      mloc = fmaxf(mloc, e);
    }
  }
  float mm = mloc;
#pragma unroll
  for (int off = 4; off < 64; off <<= 1) mm = fmaxf(mm, __shfl_xor(mm, off));

  float vreg[4];
  float vloc = 0.f;
#pragma unroll
  for (int c = 0; c < 4; ++c) {
    float v = (ereg[c] > -INFINITY) ? __expf(ereg[c] - mm) : 0.f;
    vreg[c] = v;
    vloc += v;
  }
  for (int j0 = 64; j0 < deg; j0 += 16) {  // rare tail
    int j = j0 + (lane >> 2);
    if (j < deg) {
      int s = csr_src[start + j];
      float e = el[s * NH + (lane & 3)] + ern;
      e = (e >= 0.f) ? e : NEG_SLOPE * e;
      vloc += __expf(e - mm);
    }
  }
  float ss = vloc;
#pragma unroll
  for (int off = 4; off < 64; off <<= 1) ss += __shfl_xor(ss, off);

  float inv_own = (ss > 0.f) ? (1.f / ss) : 0.f;
  float areg[4];
#pragma unroll
  for (int c = 0; c < 4; ++c) areg[c] = vreg[c] * inv_own;

  int head = lane >> 4;

  float4 acc = ((const float4*)bias)[lane];
  for (int c = 0; c < 4; ++c) {
    int base = c * 16;
    if (base >= deg) break;
    int cnt = deg - base;
    cnt = (cnt > 16) ? 16 : cnt;
    for (int g = 0; g < cnt; g += 8) {
      ushort4 u[8];
      float aa[8];
#pragma unroll
      for (int jj = 0; jj < 8; ++jj) {
        int j = g + jj;
        int jc = (j < cnt) ? j : (cnt - 1);   // clamp: duplicate row, a=0
        int srcl = jc * 4 + head;
        int s = __shfl(sreg[c], srcl);
        float a = __shfl(areg[c], srcl);
        aa[jj] = (j < cnt) ? a : 0.f;
        u[jj] = ((const ushort4*)(f + (size_t)s * HD))[lane];
      }
#pragma unroll
      for (int jj = 0; jj < 8; ++jj) {
        acc.x = fmaf(aa[jj], bf2f(u[jj].x), acc.x);
        acc.y = fmaf(aa[jj], bf2f(u[jj].y), acc.y);
        acc.z = fmaf(aa[jj], bf2f(u[jj].z), acc.z);
        acc.w = fmaf(aa[jj], bf2f(u[jj].w), acc.w);
      }
    }
  }
  if (deg > 64) {  // rare tail
    float mH = __shfl(mm, head);
    float sH = __shfl(ss, head);
    float erH = __shfl(ern, head);
    float invH = (sH > 0.f) ? (1.f / sH) : 0.f;
    for (int j = 64; j < deg; ++j) {
      int s = csr_src[start + j];
      float e = el[s * NH + head] + erH;
      e = (e >= 0.f) ? e : NEG_SLOPE * e;
      float a = __expf(e - mH) * invH;
      ushort4 u = ((const ushort4*)(f + (size_t)s * HD))[lane];
      acc.x = fmaf(a, bf2f(u.x), acc.x);
      acc.y = fmaf(a, bf2f(u.y), acc.y);
      acc.z = fmaf(a, bf2f(u.z), acc.z);
      acc.w = fmaf(a, bf2f(u.w), acc.w);
    }
  }

  if (act) {
    acc.x = (acc.x > 0.f) ? acc.x : __expf(acc.x) - 1.f;
    acc.y = (acc.y > 0.f) ? acc.y : __expf(acc.y) - 1.f;
    acc.z = (acc.z > 0.f) ? acc.z : __expf(acc.z) - 1.f;
    acc.w = (acc.w > 0.f) ? acc.w : __expf(acc.w) - 1.f;
  }
  ((float4*)(out + (size_t)node * HD))[lane] = acc;
}

// ============================ launch ============================
extern "C" void kernel_launch(void* const* d_in, const int* in_sizes, int n_in,
                              void* d_out, int out_size, void* d_ws, size_t ws_size,
                              hipStream_t stream) {
  const int* nids = (const int*)d_in[0];
  const int* esrc = (const int*)d_in[1];
  const int* edst = (const int*)d_in[2];
  const float* emb = (const float*)d_in[3];
  const float* W1 = (const float*)d_in[4];
  const float* al1 = (const float*)d_in[5];
  const float* ar1 = (const float*)d_in[6];
  const float* b1 = (const float*)d_in[7];
  const float* W2 = (const float*)d_in[8];
  const float* al2 = (const float*)d_in[9];
  const float* ar2 = (const float*)d_in[10];
  const float* b2 = (const float*)d_in[11];
  float* out = (float*)d_out;

  char* w = (char*)d_ws;
  size_t off = 0;
  auto alloc = [&](size_t bytes) {
    void* p = w + off;
    off += (bytes + 255) & ~(size_t)255;  // 256B-align every buffer
    return p;
  };
  __bf16* fbuf = (__bf16*)alloc((size_t)NN * HD * 2);
  float* el = (float*)alloc((size_t)NN * NH * 4);
  float* er = (float*)alloc((size_t)NN * NH * 4);
  int* row_ptr = (int*)alloc((size_t)(NN + 1) * 4);
  int* counts = (int*)alloc((size_t)NN * 4);
  int* rank = (int*)alloc((size_t)EE * 4);
  int* csr_src = (int*)alloc((size_t)EE * 4);
  int* bsums = (int*)alloc(1024);
  _Float16* W1t = (_Float16*)alloc((size_t)HD * HD * 2);
  _Float16* W2t = (_Float16*)alloc((size_t)HD * HD * 2);

  int nbN = (NN + 255) / 256;
  int nbE = (EE + 255) / 256;

  k_zero_i32<<<nbN, 256, 0, stream>>>(counts, NN);
  k_count<<<nbE, 256, 0, stream>>>(edst, counts, rank);
  k_scan1<<<nbN, 256, 0, stream>>>(counts, row_ptr, bsums);
  k_scan2<<<1, 256, 0, stream>>>(bsums, nbN);
  k_scan3<<<nbN, 256, 0, stream>>>(row_ptr, bsums);
  k_scatter<<<nbE, 256, 0, stream>>>(esrc, edst, row_ptr, rank, csr_src);
  k_prep_w2<<<512, 256, 0, stream>>>(W1, W2, W1t, W2t);

  int nbNode4 = (NN + 3) / 4;

  // ---- layer 1 ----
  k_gemm_mfma<<<256, 768, 0, stream>>>(emb, nids, W1t, al1, ar1, fbuf, el, er);
  k_aggregate<<<nbNode4, 256, 0, stream>>>(fbuf, el, er, row_ptr, csr_src, b1, out, 1);

  // ---- layer 2 ----
  k_gemm_mfma<<<256, 768, 0, stream>>>(out, nullptr, W2t, al2, ar2, fbuf, el, er);
  k_aggregate<<<nbNode4, 256, 0, stream>>>(fbuf, el, er, row_ptr, csr_src, b2, out, 0);
}